// Round 11
// baseline (167.617 us; speedup 1.0000x reference)
//
#include <hip/hip_runtime.h>
#include <hip/hip_bf16.h>

typedef __hip_bfloat16 bf16;
typedef short short8 __attribute__((ext_vector_type(8)));
typedef float f32x4 __attribute__((ext_vector_type(4)));

#define C_   128
#define N_   4096
#define NH_  8
#define HD_  16
#define FF_  2048
#define SCALE_Q 0.360673760222241f   // 0.25 * log2(e); attn uses v_exp_f32 (2^x)

__device__ __forceinline__ unsigned short f2bf_bits(float f) {
    bf16 h = __float2bfloat16(f);
    return *reinterpret_cast<unsigned short*>(&h);
}
// truncation-mode bf16 pack: 2 VALU ops vs ~10 for RNE pair (R10 post-mortem:
// conversion VALU rivals the exp2 cost). Bias <0.4% toward zero, acceptable here.
__device__ __forceinline__ unsigned int pack_trunc(float lo, float hi) {
    return (__float_as_uint(hi) & 0xffff0000u) | (__float_as_uint(lo) >> 16);
}
__device__ __forceinline__ short f2bf_trunc(float f) {
    return (short)(__float_as_uint(f) >> 16);
}
__device__ __forceinline__ float bfs2f(short s) {
    return __uint_as_float(((unsigned int)(unsigned short)s) << 16);
}
__device__ __forceinline__ float fast_exp2(float x) {
    return __builtin_amdgcn_exp2f(x);
}
__device__ __forceinline__ f32x4 mfma16(short8 a, short8 b, f32x4 c) {
    return __builtin_amdgcn_mfma_f32_16x16x32_bf16(a, b, c, 0, 0, 0);
}
__device__ __forceinline__ int kpos(int ko) { return ((ko & 15) << 1) + (ko >> 4); }

// ---------------- K0: prep — weight bf16 convert + fragment swizzle + x transpose ----------
__global__ void k_prep(const float* __restrict__ Wq, const float* __restrict__ Wk,
                       const float* __restrict__ Wv, const float* __restrict__ Wo,
                       const float* __restrict__ W1, const float* __restrict__ W2,
                       const float* __restrict__ x,
                       bf16* __restrict__ Wqkvf, bf16* __restrict__ Wof,
                       bf16* __restrict__ W1f, bf16* __restrict__ W2f,
                       bf16* __restrict__ xTf)
{
    const int i = blockIdx.x * 256 + threadIdx.x;
    if (i < 49152) {                                   // Wq|Wk|Wv : [384][128]
        const int o = i >> 7, k = i & 127;
        const float v = (o < 128) ? Wq[i] : (o < 256) ? Wk[i - 16384] : Wv[i - 32768];
        const int pk = kpos(k & 31);
        Wqkvf[(((o >> 4) << 2) + (k >> 5)) * 512 + (((pk >> 3) << 4) + (o & 15)) * 8 + (pk & 7)]
            = __float2bfloat16(v);
    } else if (i < 65536) {                            // Wo : [128][128]
        const int j = i - 49152, o = j >> 7, k = j & 127;
        const int pk = kpos(k & 31);
        Wof[(((o >> 4) << 2) + (k >> 5)) * 512 + (((pk >> 3) << 4) + (o & 15)) * 8 + (pk & 7)]
            = __float2bfloat16(Wo[j]);
    } else if (i < 327680) {                           // W1 : [2048][128]
        const int j = i - 65536, o = j >> 7, k = j & 127;
        const int pk = kpos(k & 31);
        W1f[(((o >> 4) << 2) + (k >> 5)) * 512 + (((pk >> 3) << 4) + (o & 15)) * 8 + (pk & 7)]
            = __float2bfloat16(W1[j]);
    } else if (i < 589824) {                           // W2 : [128][2048]
        const int j = i - 327680, o = j >> 11, k = j & 2047;
        const int pk = kpos(k & 31);
        W2f[(((o >> 4) << 6) + (k >> 5)) * 512 + (((pk >> 3) << 4) + (o & 15)) * 8 + (pk & 7)]
            = __float2bfloat16(W2[j]);
    } else if (i < 1114112) {                          // x : [128][4096] -> xTf A-frags
        const int j = i - 589824, c = j >> 12, n = j & 4095;
        const int pk = kpos(c & 31);
        xTf[(((n >> 4) << 2) + (c >> 5)) * 512 + (((pk >> 3) << 4) + (n & 15)) * 8 + (pk & 7)]
            = __float2bfloat16(x[j]);
    }
}

// ---------------- K1: QKV — barrier-free fragment-streaming GEMM ----------------
__global__ void __launch_bounds__(256) k_qkv(
    const bf16* __restrict__ xTf, const bf16* __restrict__ Wqkvf,
    const float* __restrict__ bq, const float* __restrict__ bk, const float* __restrict__ bv,
    bf16* __restrict__ qf, bf16* __restrict__ kf, bf16* __restrict__ vf)
{
    const int tid = threadIdx.x, wave = tid >> 6, lane = tid & 63;
    const int col = lane & 15, quad = lane >> 4;
    const int gw = blockIdx.x * 4 + wave;     // [0, 6144)
    const int rt = gw / 24, ct = gw % 24;
    f32x4 acc = {};
    #pragma unroll
    for (int c = 0; c < 4; ++c) {
        short8 a = *(const short8*)(xTf + ((size_t)(rt * 4 + c) << 9) + lane * 8);
        short8 b = *(const short8*)(Wqkvf + ((size_t)(ct * 4 + c) << 9) + lane * 8);
        acc = mfma16(a, b, acc);
    }
    #pragma unroll
    for (int r = 0; r < 4; ++r) {
        const int m = rt * 16 + quad * 4 + r;
        const int n = ct * 16 + col;
        const float v = acc[r];
        if (n < 128) {
            const int h = n >> 4, ch = n & 15;
            qf[((h << 8) + (m >> 4)) * 256 + (((ch >> 3) << 4) + (m & 15)) * 8 + (ch & 7)] =
                __float2bfloat16((v + bq[n]) * SCALE_Q);
        } else if (n < 256) {
            const int c2 = n - 128, h = c2 >> 4, ch = c2 & 15;
            kf[((h << 8) + (m >> 4)) * 256 + (((ch >> 3) << 4) + (m & 15)) * 8 + (ch & 7)] =
                __float2bfloat16(v + bk[c2]);
        } else {
            const int c2 = n - 256, h = c2 >> 4, ch = c2 & 15;
            const int ko = m & 31;
            const int pos = ((ko & 15) << 1) + (ko >> 4);
            vf[((h << 7) + (m >> 5)) * 512 + (((pos >> 3) << 4) + ch) * 8 + (pos & 7)] =
                __float2bfloat16(v + bv[c2]);
        }
    }
}

// ---------------- K2: MFMA flash attention (trunc-packed P) ----------------
__global__ void __launch_bounds__(256)
attn_kernel(const bf16* __restrict__ qf, const bf16* __restrict__ kf,
            const bf16* __restrict__ vf, bf16* __restrict__ af)
{
    __shared__ __align__(16) union {
        unsigned int P[4][2][320];
        float comb[4][64][8];
    } sh;
    const int tid = threadIdx.x, wave = tid >> 6, lane = tid & 63;
    const int col = lane & 15, quad = lane >> 4;
    const int gw = blockIdx.x;                   // [0, 2048)
    const int h  = gw >> 8;
    const int tile = gw & 255;
    const f32x4 zero = {};

    short8 aq = {};
    if (quad < 2)
        aq = *(const short8*)(qf + ((size_t)((h << 8) + tile) << 8) + lane * 8);

    f32x4 accO = {};
    float L[4] = {0.f, 0.f, 0.f, 0.f};

    const int kbeg = wave << 10;
    for (int i = 0; i < 32; ++i) {
        const int m0 = kbeg + (i << 5);
        unsigned int* Pw = &sh.P[wave][i & 1][0];
        const short* Ps = (const short*)Pw;

        short8 bk0 = {}, bk1 = {};
        if (quad < 2) {
            const bf16* kb = kf + ((size_t)((h << 8) + (m0 >> 4)) << 8) + lane * 8;
            bk0 = *(const short8*)(kb);
            bk1 = *(const short8*)(kb + 256);
        }
        f32x4 s0 = mfma16(aq, bk0, zero);
        f32x4 s1 = mfma16(aq, bk1, zero);
        #pragma unroll
        for (int r = 0; r < 4; ++r) {
            const float p0 = fast_exp2(s0[r]);
            const float p1 = fast_exp2(s1[r]);
            L[r] += p0 + p1;
            Pw[(quad * 4 + r) * 20 + col] = pack_trunc(p0, p1);
        }
        short8 ap = *(const short8*)(Ps + col * 40 + quad * 8);
        short8 bv_ = *(const short8*)(vf + ((size_t)((h << 7) + (m0 >> 5)) << 9) + lane * 8);
        accO = mfma16(ap, bv_, accO);
    }

    __syncthreads();
    #pragma unroll
    for (int r = 0; r < 4; ++r) {
        sh.comb[wave][lane][r]     = accO[r];
        sh.comb[wave][lane][4 + r] = L[r];
    }
    __syncthreads();

    if (wave == 0) {
        #pragma unroll
        for (int r = 0; r < 4; ++r) {
            float O = sh.comb[0][lane][r] + sh.comb[1][lane][r]
                    + sh.comb[2][lane][r] + sh.comb[3][lane][r];
            float l = sh.comb[0][lane][4+r] + sh.comb[1][lane][4+r]
                    + sh.comb[2][lane][4+r] + sh.comb[3][lane][4+r];
            l += __shfl_xor(l, 1); l += __shfl_xor(l, 2);
            l += __shfl_xor(l, 4); l += __shfl_xor(l, 8);
            const int row16 = quad * 4 + r;
            const int pk = (col << 1) + (h & 1);
            af[((tile << 2) + (h >> 1)) * 512 + (((pk >> 3) << 4) + row16) * 8 + (pk & 7)] =
                __float2bfloat16(O / l);
        }
    }
}

// ---------------- K3: MEGA — oproj + LN1 + FFN1 + FFN2 + LN2 ----------------
// R10 post-mortem: 4 waves/block on 256 blocks = 1 wave/SIMD, zero TLP.
// Now 512 threads / 8 waves (2 waves/SIMD); each wave owns a 256-FF slice;
// FFN2 partials combined with LDS atomic float adds (28.7 KB static LDS).
__global__ void __launch_bounds__(512, 1)
k_mega(const bf16* __restrict__ af, const bf16* __restrict__ xTf,
       const bf16* __restrict__ Wof, const bf16* __restrict__ W1f, const bf16* __restrict__ W2f,
       const float* __restrict__ bo, const float* __restrict__ b1, const float* __restrict__ b2,
       const float* __restrict__ g1, const float* __restrict__ be1,
       const float* __restrict__ g2, const float* __restrict__ be2,
       float* __restrict__ out)
{
    __shared__ __align__(16) unsigned int Pb[8][2][320];   // 20.5 KB per-wave transpose dbuf
    __shared__ float comb[32][64];                          // 8 KB ffn2 accumulators
    const int tid = threadIdx.x, wave = tid >> 6, lane = tid & 63;
    const int col = lane & 15, quad = lane >> 4;
    const int rt = blockIdx.x, n0 = rt << 4;
    const f32x4 zero = {};

    for (int i = tid; i < 2048; i += 512) ((float*)comb)[i] = 0.f;
    __syncthreads();

    // ---- oproj (each wave redundantly): D = attn_frag . Wo^T ----
    short8 ao[4], xt[4];
    #pragma unroll
    for (int c = 0; c < 4; ++c) {
        ao[c] = *(const short8*)(af  + ((size_t)(rt * 4 + c) << 9) + lane * 8);
        xt[c] = *(const short8*)(xTf + ((size_t)(rt * 4 + c) << 9) + lane * 8);
    }
    f32x4 d[8];
    #pragma unroll
    for (int t = 0; t < 8; ++t) d[t] = zero;
    #pragma unroll
    for (int t = 0; t < 8; ++t)
        #pragma unroll
        for (int c = 0; c < 4; ++c) {
            short8 b = *(const short8*)(Wof + ((size_t)(t * 4 + c) << 9) + lane * 8);
            d[t] = mfma16(ao[c], b, d[t]);
        }
    #pragma unroll
    for (int t = 0; t < 8; ++t) {
        const float bt = bo[t * 16 + col];
        #pragma unroll
        for (int r = 0; r < 4; ++r) d[t][r] += bt;
    }

    // ---- D->A transpose via wave-private LDS; add residual x ----
    float x1f[4][8];
    #pragma unroll
    for (int c = 0; c < 4; ++c) {
        unsigned int* Pw = &Pb[wave][c & 1][0];
        const short* Ps = (const short*)Pw;
        #pragma unroll
        for (int r = 0; r < 4; ++r)
            Pw[(quad * 4 + r) * 20 + col] = pack_trunc(d[2 * c][r], d[2 * c + 1][r]);
        short8 ar = *(const short8*)(Ps + col * 40 + quad * 8);
        #pragma unroll
        for (int j = 0; j < 8; ++j)
            x1f[c][j] = bfs2f(ar[j]) + bfs2f(xt[c][j]);
    }

    // ---- LN1 ----
    float s = 0.f, ss = 0.f;
    #pragma unroll
    for (int c = 0; c < 4; ++c)
        #pragma unroll
        for (int j = 0; j < 8; ++j) { s += x1f[c][j]; ss += x1f[c][j] * x1f[c][j]; }
    s  += __shfl_xor(s, 16);  s  += __shfl_xor(s, 32);
    ss += __shfl_xor(ss, 16); ss += __shfl_xor(ss, 32);
    const float m1 = s * (1.f / 128.f);
    const float rstd1 = rsqrtf(ss * (1.f / 128.f) - m1 * m1 + 1e-5f);
    short8 aq1[4];
    #pragma unroll
    for (int c = 0; c < 4; ++c)
        #pragma unroll
        for (int j = 0; j < 8; ++j) {
            const int pos = quad * 8 + j;
            const int ko = ((pos & 1) << 4) + (pos >> 1);
            const int ch = c * 32 + ko;
            aq1[c][j] = f2bf_trunc((x1f[c][j] - m1) * rstd1 * g1[ch] + be1[ch]);
        }

    // ---- FFN: this wave owns FF range [wave*256, +256) = 8 chunks of 32 ----
    f32x4 ACC[8];
    #pragma unroll
    for (int t = 0; t < 8; ++t) ACC[t] = zero;
    for (int i = 0; i < 8; ++i) {
        const int ffc = (wave << 3) + i;                  // global 32-FF chunk [0,64)
        f32x4 p0 = zero, p1 = zero;
        #pragma unroll
        for (int c = 0; c < 4; ++c) {
            short8 b = *(const short8*)(W1f + ((size_t)(ffc * 8 + c) << 9) + lane * 8);
            p0 = mfma16(aq1[c], b, p0);
        }
        #pragma unroll
        for (int c = 0; c < 4; ++c) {
            short8 b = *(const short8*)(W1f + ((size_t)(ffc * 8 + 4 + c) << 9) + lane * 8);
            p1 = mfma16(aq1[c], b, p1);
        }
        const float bb0 = b1[ffc * 32 + col], bb1 = b1[ffc * 32 + 16 + col];
        unsigned int* Pw = &Pb[wave][i & 1][0];
        #pragma unroll
        for (int r = 0; r < 4; ++r)
            Pw[(quad * 4 + r) * 20 + col] =
                pack_trunc(fmaxf(p0[r] + bb0, 0.f), fmaxf(p1[r] + bb1, 0.f));
        short8 ah = *(const short8*)((const short*)Pw + col * 40 + quad * 8);
        #pragma unroll
        for (int t = 0; t < 8; ++t) {
            short8 bw = *(const short8*)(W2f + ((size_t)(t * 64 + ffc) << 9) + lane * 8);
            ACC[t] = mfma16(ah, bw, ACC[t]);
        }
    }

    // ---- combine ffn2 partials (LDS atomic), then wave0: residual + LN2 + store ----
    #pragma unroll
    for (int t = 0; t < 8; ++t)
        #pragma unroll
        for (int r = 0; r < 4; ++r)
            atomicAdd(&comb[t * 4 + r][lane], ACC[t][r]);
    __syncthreads();
    if (wave == 0) {
        // recover x1n in D-layout from aq1 A-frags via LDS (Pb dead post-barrier)
        short* xb = (short*)&Pb[0][0][0];   // [row16][chunk][32 pk] = 4096 shorts
        #pragma unroll
        for (int c = 0; c < 4; ++c)
            *(short8*)(xb + (col * 4 + c) * 32 + quad * 8) = aq1[c];
        float t2[8][4];
        #pragma unroll
        for (int t = 0; t < 8; ++t) {
            const int ch = t * 16 + col;
            const int pk = (col << 1) + (t & 1);
            const int c = t >> 1;
            const float bb = b2[ch];
            #pragma unroll
            for (int r = 0; r < 4; ++r)
                t2[t][r] = comb[t * 4 + r][lane] + bb
                         + bfs2f(xb[((quad * 4 + r) * 4 + c) * 32 + pk]);
        }
        #pragma unroll
        for (int r = 0; r < 4; ++r) {
            float S = 0.f, SS = 0.f;
            #pragma unroll
            for (int t = 0; t < 8; ++t) { S += t2[t][r]; SS += t2[t][r] * t2[t][r]; }
            S  += __shfl_xor(S, 1);  S  += __shfl_xor(S, 2);
            S  += __shfl_xor(S, 4);  S  += __shfl_xor(S, 8);
            SS += __shfl_xor(SS, 1); SS += __shfl_xor(SS, 2);
            SS += __shfl_xor(SS, 4); SS += __shfl_xor(SS, 8);
            const float m2 = S * (1.f / 128.f);
            const float rstd2 = rsqrtf(SS * (1.f / 128.f) - m2 * m2 + 1e-5f);
            #pragma unroll
            for (int t = 0; t < 8; ++t) {
                const int ch = t * 16 + col;
                out[(size_t)ch * N_ + n0 + quad * 4 + r] =
                    (t2[t][r] - m2) * rstd2 * g2[ch] + be2[ch];
            }
        }
    }
}

extern "C" void kernel_launch(void* const* d_in, const int* in_sizes, int n_in,
                              void* d_out, int out_size, void* d_ws, size_t ws_size,
                              hipStream_t stream) {
    const float* x   = (const float*)d_in[0];
    const float* Wq  = (const float*)d_in[1];
    const float* bq  = (const float*)d_in[2];
    const float* Wk  = (const float*)d_in[3];
    const float* bk  = (const float*)d_in[4];
    const float* Wv  = (const float*)d_in[5];
    const float* bv  = (const float*)d_in[6];
    const float* Wo  = (const float*)d_in[7];
    const float* bo  = (const float*)d_in[8];
    const float* W1  = (const float*)d_in[9];
    const float* b1  = (const float*)d_in[10];
    const float* W2  = (const float*)d_in[11];
    const float* b2  = (const float*)d_in[12];
    const float* g1  = (const float*)d_in[13];
    const float* be1 = (const float*)d_in[14];
    const float* g2  = (const float*)d_in[15];
    const float* be2 = (const float*)d_in[16];
    float* out = (float*)d_out;

    char* ws = (char*)d_ws;
    bf16* xTf   = (bf16*)(ws + 0);          // 1 MB
    bf16* qf    = (bf16*)(ws + 1048576);    // 1 MB
    bf16* kf    = (bf16*)(ws + 2097152);    // 1 MB
    bf16* vf    = (bf16*)(ws + 3145728);    // 1 MB
    bf16* af    = (bf16*)(ws + 4194304);    // 1 MB
    bf16* Wqkvf = (bf16*)(ws + 5242880);    // 96 KB
    bf16* Wof   = (bf16*)(ws + 5341184);    // 32 KB
    bf16* W1f   = (bf16*)(ws + 5373952);    // 512 KB
    bf16* W2f   = (bf16*)(ws + 5898240);    // 512 KB

    k_prep<<<4352, 256, 0, stream>>>(Wq, Wk, Wv, Wo, W1, W2, x, Wqkvf, Wof, W1f, W2f, xTf);
    k_qkv<<<1536, 256, 0, stream>>>(xTf, Wqkvf, bq, bk, bv, qf, kf, vf);
    attn_kernel<<<2048, 256, 0, stream>>>(qf, kf, vf, af);
    k_mega<<<256, 512, 0, stream>>>(af, xTf, Wof, W1f, W2f, bo, b1, b2,
                                    g1, be1, g2, be2, out);
}

// Round 12
// 143.404 us; speedup vs baseline: 1.1688x; 1.1688x over previous
//
#include <hip/hip_runtime.h>
#include <hip/hip_bf16.h>

typedef __hip_bfloat16 bf16;
typedef short short8 __attribute__((ext_vector_type(8)));
typedef float f32x4 __attribute__((ext_vector_type(4)));

#define C_   128
#define N_   4096
#define NH_  8
#define HD_  16
#define FF_  2048
#define SCALE_Q 0.360673760222241f   // 0.25 * log2(e); attn uses v_exp_f32 (2^x)

__device__ __forceinline__ unsigned short f2bf_bits(float f) {
    bf16 h = __float2bfloat16(f);
    return *reinterpret_cast<unsigned short*>(&h);
}
// truncation-mode bf16 pack: 2 VALU ops vs ~10 for RNE pair. R11 verified
// accuracy-neutral (absmax 0.03125 unchanged).
__device__ __forceinline__ unsigned int pack_trunc(float lo, float hi) {
    return (__float_as_uint(hi) & 0xffff0000u) | (__float_as_uint(lo) >> 16);
}
__device__ __forceinline__ short f2bf_trunc(float f) {
    return (short)(__float_as_uint(f) >> 16);
}
__device__ __forceinline__ float bfs2f(short s) {
    return __uint_as_float(((unsigned int)(unsigned short)s) << 16);
}
__device__ __forceinline__ float fast_exp2(float x) {
    return __builtin_amdgcn_exp2f(x);
}
__device__ __forceinline__ f32x4 mfma16(short8 a, short8 b, f32x4 c) {
    return __builtin_amdgcn_mfma_f32_16x16x32_bf16(a, b, c, 0, 0, 0);
}
__device__ __forceinline__ int kpos(int ko) { return ((ko & 15) << 1) + (ko >> 4); }

// ---------------- K0: prep — weight bf16 convert + fragment swizzle + x transpose ----------
__global__ void k_prep(const float* __restrict__ Wq, const float* __restrict__ Wk,
                       const float* __restrict__ Wv, const float* __restrict__ Wo,
                       const float* __restrict__ W1, const float* __restrict__ W2,
                       const float* __restrict__ x,
                       bf16* __restrict__ Wqkvf, bf16* __restrict__ Wof,
                       bf16* __restrict__ W1f, bf16* __restrict__ W2f,
                       bf16* __restrict__ xTf)
{
    const int i = blockIdx.x * 256 + threadIdx.x;
    if (i < 49152) {                                   // Wq|Wk|Wv : [384][128]
        const int o = i >> 7, k = i & 127;
        const float v = (o < 128) ? Wq[i] : (o < 256) ? Wk[i - 16384] : Wv[i - 32768];
        const int pk = kpos(k & 31);
        Wqkvf[(((o >> 4) << 2) + (k >> 5)) * 512 + (((pk >> 3) << 4) + (o & 15)) * 8 + (pk & 7)]
            = __float2bfloat16(v);
    } else if (i < 65536) {                            // Wo : [128][128]
        const int j = i - 49152, o = j >> 7, k = j & 127;
        const int pk = kpos(k & 31);
        Wof[(((o >> 4) << 2) + (k >> 5)) * 512 + (((pk >> 3) << 4) + (o & 15)) * 8 + (pk & 7)]
            = __float2bfloat16(Wo[j]);
    } else if (i < 327680) {                           // W1 : [2048][128]
        const int j = i - 65536, o = j >> 7, k = j & 127;
        const int pk = kpos(k & 31);
        W1f[(((o >> 4) << 2) + (k >> 5)) * 512 + (((pk >> 3) << 4) + (o & 15)) * 8 + (pk & 7)]
            = __float2bfloat16(W1[j]);
    } else if (i < 589824) {                           // W2 : [128][2048]
        const int j = i - 327680, o = j >> 11, k = j & 2047;
        const int pk = kpos(k & 31);
        W2f[(((o >> 4) << 6) + (k >> 5)) * 512 + (((pk >> 3) << 4) + (o & 15)) * 8 + (pk & 7)]
            = __float2bfloat16(W2[j]);
    } else if (i < 1114112) {                          // x : [128][4096] -> xTf A-frags
        const int j = i - 589824, c = j >> 12, n = j & 4095;
        const int pk = kpos(c & 31);
        xTf[(((n >> 4) << 2) + (c >> 5)) * 512 + (((pk >> 3) << 4) + (n & 15)) * 8 + (pk & 7)]
            = __float2bfloat16(x[j]);
    }
}

// ---------------- K1: QKV — barrier-free fragment-streaming GEMM ----------------
__global__ void __launch_bounds__(256) k_qkv(
    const bf16* __restrict__ xTf, const bf16* __restrict__ Wqkvf,
    const float* __restrict__ bq, const float* __restrict__ bk, const float* __restrict__ bv,
    bf16* __restrict__ qf, bf16* __restrict__ kf, bf16* __restrict__ vf)
{
    const int tid = threadIdx.x, wave = tid >> 6, lane = tid & 63;
    const int col = lane & 15, quad = lane >> 4;
    const int gw = blockIdx.x * 4 + wave;     // [0, 6144)
    const int rt = gw / 24, ct = gw % 24;
    f32x4 acc = {};
    #pragma unroll
    for (int c = 0; c < 4; ++c) {
        short8 a = *(const short8*)(xTf + ((size_t)(rt * 4 + c) << 9) + lane * 8);
        short8 b = *(const short8*)(Wqkvf + ((size_t)(ct * 4 + c) << 9) + lane * 8);
        acc = mfma16(a, b, acc);
    }
    #pragma unroll
    for (int r = 0; r < 4; ++r) {
        const int m = rt * 16 + quad * 4 + r;
        const int n = ct * 16 + col;
        const float v = acc[r];
        if (n < 128) {
            const int h = n >> 4, ch = n & 15;
            qf[((h << 8) + (m >> 4)) * 256 + (((ch >> 3) << 4) + (m & 15)) * 8 + (ch & 7)] =
                __float2bfloat16((v + bq[n]) * SCALE_Q);
        } else if (n < 256) {
            const int c2 = n - 128, h = c2 >> 4, ch = c2 & 15;
            kf[((h << 8) + (m >> 4)) * 256 + (((ch >> 3) << 4) + (m & 15)) * 8 + (ch & 7)] =
                __float2bfloat16(v + bk[c2]);
        } else {
            const int c2 = n - 256, h = c2 >> 4, ch = c2 & 15;
            const int ko = m & 31;
            const int pos = ((ko & 15) << 1) + (ko >> 4);
            vf[((h << 7) + (m >> 5)) * 512 + (((pos >> 3) << 4) + ch) * 8 + (pos & 7)] =
                __float2bfloat16(v + bv[c2]);
        }
    }
}

// ---------------- K2: MFMA flash attention — dual-chunk ILP ----------------
// R11 post-mortem: single serial chain per wave (MFMA->exp2->pack->LDS rt->MFMA).
// Now 2 chunks in flight with independent accumulators and both P buffers live
// concurrently: chunk B's score/exp work overlaps chunk A's LDS round-trip.
__global__ void __launch_bounds__(256)
attn_kernel(const bf16* __restrict__ qf, const bf16* __restrict__ kf,
            const bf16* __restrict__ vf, bf16* __restrict__ af)
{
    __shared__ __align__(16) union {
        unsigned int P[4][2][320];
        float comb[4][64][8];
    } sh;
    const int tid = threadIdx.x, wave = tid >> 6, lane = tid & 63;
    const int col = lane & 15, quad = lane >> 4;
    const int gw = blockIdx.x;                   // [0, 2048)
    const int h  = gw >> 8;
    const int tile = gw & 255;
    const f32x4 zero = {};

    short8 aq = {};
    if (quad < 2)
        aq = *(const short8*)(qf + ((size_t)((h << 8) + tile) << 8) + lane * 8);

    f32x4 accO0 = {}, accO1 = {};
    float L[4] = {0.f, 0.f, 0.f, 0.f};

    const int kbeg = wave << 10;
    unsigned int* P0 = &sh.P[wave][0][0];
    unsigned int* P1 = &sh.P[wave][1][0];

    for (int i = 0; i < 32; i += 2) {
        const int mA = kbeg + (i << 5);
        const int mB = mA + 32;

        short8 bkA0 = {}, bkA1 = {}, bkB0 = {}, bkB1 = {};
        if (quad < 2) {
            const bf16* ka = kf + ((size_t)((h << 8) + (mA >> 4)) << 8) + lane * 8;
            bkA0 = *(const short8*)(ka);
            bkA1 = *(const short8*)(ka + 256);
            bkB0 = *(const short8*)(ka + 512);
            bkB1 = *(const short8*)(ka + 768);
        }
        f32x4 s0 = mfma16(aq, bkA0, zero);
        f32x4 s1 = mfma16(aq, bkA1, zero);
        f32x4 s2 = mfma16(aq, bkB0, zero);
        f32x4 s3 = mfma16(aq, bkB1, zero);
        #pragma unroll
        for (int r = 0; r < 4; ++r) {
            const float p0 = fast_exp2(s0[r]);
            const float p1 = fast_exp2(s1[r]);
            const float p2 = fast_exp2(s2[r]);
            const float p3 = fast_exp2(s3[r]);
            L[r] += (p0 + p1) + (p2 + p3);
            P0[(quad * 4 + r) * 20 + col] = pack_trunc(p0, p1);
            P1[(quad * 4 + r) * 20 + col] = pack_trunc(p2, p3);
        }
        short8 vA = *(const short8*)(vf + ((size_t)((h << 7) + (mA >> 5)) << 9) + lane * 8);
        short8 vB = *(const short8*)(vf + ((size_t)((h << 7) + (mB >> 5)) << 9) + lane * 8);
        short8 ap0 = *(const short8*)((const short*)P0 + col * 40 + quad * 8);
        accO0 = mfma16(ap0, vA, accO0);
        short8 ap1 = *(const short8*)((const short*)P1 + col * 40 + quad * 8);
        accO1 = mfma16(ap1, vB, accO1);
    }

    f32x4 accO;
    #pragma unroll
    for (int r = 0; r < 4; ++r) accO[r] = accO0[r] + accO1[r];

    __syncthreads();
    #pragma unroll
    for (int r = 0; r < 4; ++r) {
        sh.comb[wave][lane][r]     = accO[r];
        sh.comb[wave][lane][4 + r] = L[r];
    }
    __syncthreads();

    if (wave == 0) {
        #pragma unroll
        for (int r = 0; r < 4; ++r) {
            float O = sh.comb[0][lane][r] + sh.comb[1][lane][r]
                    + sh.comb[2][lane][r] + sh.comb[3][lane][r];
            float l = sh.comb[0][lane][4+r] + sh.comb[1][lane][4+r]
                    + sh.comb[2][lane][4+r] + sh.comb[3][lane][4+r];
            l += __shfl_xor(l, 1); l += __shfl_xor(l, 2);
            l += __shfl_xor(l, 4); l += __shfl_xor(l, 8);
            const int row16 = quad * 4 + r;
            const int pk = (col << 1) + (h & 1);
            af[((tile << 2) + (h >> 1)) * 512 + (((pk >> 3) << 4) + row16) * 8 + (pk & 7)] =
                __float2bfloat16(O / l);
        }
    }
}

// ---------------- K3: MEGA — oproj + LN1 + FFN1 + FFN2 + LN2 (R10 proven shape) -----------
// 4 waves / 256 threads, 1 block per 16-row tile. R11's 8-wave variant regressed
// (41.7 vs ~24 us): 8x redundant oproj + LDS-atomic combine serialization.
__global__ void __launch_bounds__(256, 1)
k_mega(const bf16* __restrict__ af, const bf16* __restrict__ xTf,
       const bf16* __restrict__ Wof, const bf16* __restrict__ W1f, const bf16* __restrict__ W2f,
       const float* __restrict__ bo, const float* __restrict__ b1, const float* __restrict__ b2,
       const float* __restrict__ g1, const float* __restrict__ be1,
       const float* __restrict__ g2, const float* __restrict__ be2,
       float* __restrict__ out)
{
    __shared__ __align__(16) unsigned int Pb[4][2][320];   // per-wave transpose dbuf (10 KB)
    __shared__ float comb[96][64];                          // ffn2 partials, waves 1-3 (24 KB)
    const int tid = threadIdx.x, wave = tid >> 6, lane = tid & 63;
    const int col = lane & 15, quad = lane >> 4;
    const int rt = blockIdx.x, n0 = rt << 4;
    const f32x4 zero = {};

    // ---- oproj: D = attn_frag . Wo^T  (each wave redundantly) ----
    short8 ao[4], xt[4];
    #pragma unroll
    for (int c = 0; c < 4; ++c) {
        ao[c] = *(const short8*)(af  + ((size_t)(rt * 4 + c) << 9) + lane * 8);
        xt[c] = *(const short8*)(xTf + ((size_t)(rt * 4 + c) << 9) + lane * 8);
    }
    f32x4 d[8];
    #pragma unroll
    for (int t = 0; t < 8; ++t) d[t] = zero;
    #pragma unroll
    for (int t = 0; t < 8; ++t)
        #pragma unroll
        for (int c = 0; c < 4; ++c) {
            short8 b = *(const short8*)(Wof + ((size_t)(t * 4 + c) << 9) + lane * 8);
            d[t] = mfma16(ao[c], b, d[t]);
        }
    #pragma unroll
    for (int t = 0; t < 8; ++t) {
        const float bt = bo[t * 16 + col];
        #pragma unroll
        for (int r = 0; r < 4; ++r) d[t][r] += bt;
    }

    // ---- D->A transpose via wave-private LDS; add residual x ----
    float x1f[4][8];
    #pragma unroll
    for (int c = 0; c < 4; ++c) {
        unsigned int* Pw = &Pb[wave][c & 1][0];
        const short* Ps = (const short*)Pw;
        #pragma unroll
        for (int r = 0; r < 4; ++r)
            Pw[(quad * 4 + r) * 20 + col] = pack_trunc(d[2 * c][r], d[2 * c + 1][r]);
        short8 ar = *(const short8*)(Ps + col * 40 + quad * 8);
        #pragma unroll
        for (int j = 0; j < 8; ++j)
            x1f[c][j] = bfs2f(ar[j]) + bfs2f(xt[c][j]);
    }

    // ---- LN1 ----
    float s = 0.f, ss = 0.f;
    #pragma unroll
    for (int c = 0; c < 4; ++c)
        #pragma unroll
        for (int j = 0; j < 8; ++j) { s += x1f[c][j]; ss += x1f[c][j] * x1f[c][j]; }
    s  += __shfl_xor(s, 16);  s  += __shfl_xor(s, 32);
    ss += __shfl_xor(ss, 16); ss += __shfl_xor(ss, 32);
    const float m1 = s * (1.f / 128.f);
    const float rstd1 = rsqrtf(ss * (1.f / 128.f) - m1 * m1 + 1e-5f);
    short8 aq1[4];
    #pragma unroll
    for (int c = 0; c < 4; ++c)
        #pragma unroll
        for (int j = 0; j < 8; ++j) {
            const int pos = quad * 8 + j;
            const int ko = ((pos & 1) << 4) + (pos >> 1);
            const int ch = c * 32 + ko;
            aq1[c][j] = f2bf_trunc((x1f[c][j] - m1) * rstd1 * g1[ch] + be1[ch]);
        }

    // ---- FFN: this wave owns FF range [wave*512, +512) = 16 chunks of 32 ----
    f32x4 ACC[8];
    #pragma unroll
    for (int t = 0; t < 8; ++t) ACC[t] = zero;
    for (int i = 0; i < 16; ++i) {
        const int ffc = (wave << 4) + i;                  // global 32-FF chunk [0,64)
        f32x4 p0 = zero, p1 = zero;
        #pragma unroll
        for (int c = 0; c < 4; ++c) {
            short8 b = *(const short8*)(W1f + ((size_t)(ffc * 8 + c) << 9) + lane * 8);
            p0 = mfma16(aq1[c], b, p0);
        }
        #pragma unroll
        for (int c = 0; c < 4; ++c) {
            short8 b = *(const short8*)(W1f + ((size_t)(ffc * 8 + 4 + c) << 9) + lane * 8);
            p1 = mfma16(aq1[c], b, p1);
        }
        const float bb0 = b1[ffc * 32 + col], bb1 = b1[ffc * 32 + 16 + col];
        unsigned int* Pw = &Pb[wave][i & 1][0];
        #pragma unroll
        for (int r = 0; r < 4; ++r)
            Pw[(quad * 4 + r) * 20 + col] =
                pack_trunc(fmaxf(p0[r] + bb0, 0.f), fmaxf(p1[r] + bb1, 0.f));
        short8 ah = *(const short8*)((const short*)Pw + col * 40 + quad * 8);
        #pragma unroll
        for (int t = 0; t < 8; ++t) {
            short8 bw = *(const short8*)(W2f + ((size_t)(t * 64 + ffc) << 9) + lane * 8);
            ACC[t] = mfma16(ah, bw, ACC[t]);
        }
    }

    // ---- combine ffn2 partials; wave0: residual + LN2 + store ----
    if (wave) {
        #pragma unroll
        for (int t = 0; t < 8; ++t)
            #pragma unroll
            for (int r = 0; r < 4; ++r)
                comb[(wave - 1) * 32 + t * 4 + r][lane] = ACC[t][r];
    }
    __syncthreads();
    if (wave == 0) {
        #pragma unroll
        for (int t = 0; t < 8; ++t)
            #pragma unroll
            for (int r = 0; r < 4; ++r)
                ACC[t][r] += comb[t * 4 + r][lane] + comb[32 + t * 4 + r][lane]
                           + comb[64 + t * 4 + r][lane];
        // recover x1n in D-layout from aq1 A-frags via LDS (Pb dead post-barrier)
        short* xb = (short*)&Pb[0][0][0];   // [row16][chunk][32 pk] = 4096 shorts
        #pragma unroll
        for (int c = 0; c < 4; ++c)
            *(short8*)(xb + (col * 4 + c) * 32 + quad * 8) = aq1[c];
        float t2[8][4];
        #pragma unroll
        for (int t = 0; t < 8; ++t) {
            const int ch = t * 16 + col;
            const int pk = (col << 1) + (t & 1);
            const int c = t >> 1;
            const float bb = b2[ch];
            #pragma unroll
            for (int r = 0; r < 4; ++r)
                t2[t][r] = ACC[t][r] + bb + bfs2f(xb[((quad * 4 + r) * 4 + c) * 32 + pk]);
        }
        #pragma unroll
        for (int r = 0; r < 4; ++r) {
            float S = 0.f, SS = 0.f;
            #pragma unroll
            for (int t = 0; t < 8; ++t) { S += t2[t][r]; SS += t2[t][r] * t2[t][r]; }
            S  += __shfl_xor(S, 1);  S  += __shfl_xor(S, 2);
            S  += __shfl_xor(S, 4);  S  += __shfl_xor(S, 8);
            SS += __shfl_xor(SS, 1); SS += __shfl_xor(SS, 2);
            SS += __shfl_xor(SS, 4); SS += __shfl_xor(SS, 8);
            const float m2 = S * (1.f / 128.f);
            const float rstd2 = rsqrtf(SS * (1.f / 128.f) - m2 * m2 + 1e-5f);
            #pragma unroll
            for (int t = 0; t < 8; ++t) {
                const int ch = t * 16 + col;
                out[(size_t)ch * N_ + n0 + quad * 4 + r] =
                    (t2[t][r] - m2) * rstd2 * g2[ch] + be2[ch];
            }
        }
    }
}

extern "C" void kernel_launch(void* const* d_in, const int* in_sizes, int n_in,
                              void* d_out, int out_size, void* d_ws, size_t ws_size,
                              hipStream_t stream) {
    const float* x   = (const float*)d_in[0];
    const float* Wq  = (const float*)d_in[1];
    const float* bq  = (const float*)d_in[2];
    const float* Wk  = (const float*)d_in[3];
    const float* bk  = (const float*)d_in[4];
    const float* Wv  = (const float*)d_in[5];
    const float* bv  = (const float*)d_in[6];
    const float* Wo  = (const float*)d_in[7];
    const float* bo  = (const float*)d_in[8];
    const float* W1  = (const float*)d_in[9];
    const float* b1  = (const float*)d_in[10];
    const float* W2  = (const float*)d_in[11];
    const float* b2  = (const float*)d_in[12];
    const float* g1  = (const float*)d_in[13];
    const float* be1 = (const float*)d_in[14];
    const float* g2  = (const float*)d_in[15];
    const float* be2 = (const float*)d_in[16];
    float* out = (float*)d_out;

    char* ws = (char*)d_ws;
    bf16* xTf   = (bf16*)(ws + 0);          // 1 MB
    bf16* qf    = (bf16*)(ws + 1048576);    // 1 MB
    bf16* kf    = (bf16*)(ws + 2097152);    // 1 MB
    bf16* vf    = (bf16*)(ws + 3145728);    // 1 MB
    bf16* af    = (bf16*)(ws + 4194304);    // 1 MB
    bf16* Wqkvf = (bf16*)(ws + 5242880);    // 96 KB
    bf16* Wof   = (bf16*)(ws + 5341184);    // 32 KB
    bf16* W1f   = (bf16*)(ws + 5373952);    // 512 KB
    bf16* W2f   = (bf16*)(ws + 5898240);    // 512 KB

    k_prep<<<4352, 256, 0, stream>>>(Wq, Wk, Wv, Wo, W1, W2, x, Wqkvf, Wof, W1f, W2f, xTf);
    k_qkv<<<1536, 256, 0, stream>>>(xTf, Wqkvf, bq, bk, bv, qf, kf, vf);
    attn_kernel<<<2048, 256, 0, stream>>>(qf, kf, vf, af);
    k_mega<<<256, 256, 0, stream>>>(af, xTf, Wof, W1f, W2f, bo, b1, b2,
                                    g1, be1, g2, be2, out);
}